// Round 1
// baseline (301.567 us; speedup 1.0000x reference)
//
#include <hip/hip_runtime.h>

#define IN_CH 128
#define HID 64

// ---------------------------------------------------------------------------
// Kernel 1: fused encoder GEMMs.
//   y_rel[n][c] = sum_k x[n][k] * W_rel[k][c]
//   agg[n][c]   = sum_k x[n][k] * W_root[k][c] + b_rel[c]   (scatter target init)
// Block: 256 threads, tile of 32 nodes. Weights staged in LDS in two k-halves
// (keeps static LDS at ~49 KB -> 3 blocks/CU). Thread (tr=t>>5, tc=t&31)
// computes a 4-node x 4-col tile of ONE matrix (tc<16: W_rel, tc>=16: W_root).
// ---------------------------------------------------------------------------
__global__ __launch_bounds__(256) void graphmae_encode(
    const float* __restrict__ x, const float* __restrict__ W_rel,
    const float* __restrict__ b_rel, const float* __restrict__ W_root,
    float* __restrict__ y_rel, float* __restrict__ agg, int N)
{
    __shared__ float lw[64 * 128];   // k-half of [W_rel | W_root]; row=k_local, cols [rel 0..63 | root 0..63]
    __shared__ float xs[32 * 132];   // 32 x-rows, padded 128->132 (keeps 16B alignment, breaks pow2 stride)

    const int t  = threadIdx.x;
    const int tc = t & 31;
    const int tr = t >> 5;
    const int n0 = blockIdx.x * 32;

    // ---- stage x tile (32 rows x 128 f32), coalesced float4 ----
    #pragma unroll
    for (int p = 0; p < 4; ++p) {
        const int row = tr + p * 8;
        const int n   = n0 + row;
        float4 v = make_float4(0.f, 0.f, 0.f, 0.f);
        if (n < N) v = *(const float4*)(x + (size_t)n * IN_CH + tc * 4);
        *(float4*)(xs + row * 132 + tc * 4) = v;
    }

    float acc[4][4];
    #pragma unroll
    for (int i = 0; i < 4; ++i)
        #pragma unroll
        for (int j = 0; j < 4; ++j) acc[i][j] = 0.f;

    for (int kh = 0; kh < 2; ++kh) {
        __syncthreads();   // waves done with previous lw contents (and xs staged)
        // ---- stage weight k-half: rows kh*64 .. kh*64+63 of both matrices ----
        #pragma unroll
        for (int p = 0; p < 8; ++p) {
            const int idx  = t + p * 256;       // float4 index, 0..2047
            const int krow = idx >> 5;          // 0..63
            const int col4 = (idx & 31) * 4;    // 0..124
            float4 v;
            if (col4 < HID)
                v = *(const float4*)(W_rel  + (size_t)(kh * 64 + krow) * HID + col4);
            else
                v = *(const float4*)(W_root + (size_t)(kh * 64 + krow) * HID + (col4 - HID));
            *(float4*)(lw + idx * 4) = v;
        }
        __syncthreads();

        // ---- compute: per 4-k step: 8x ds_read_b128, 64 v_fma_f32 ----
        #pragma unroll 2
        for (int k = 0; k < 64; k += 4) {
            float4 w0 = *(const float4*)(lw + (k + 0) * 128 + tc * 4);
            float4 w1 = *(const float4*)(lw + (k + 1) * 128 + tc * 4);
            float4 w2 = *(const float4*)(lw + (k + 2) * 128 + tc * 4);
            float4 w3 = *(const float4*)(lw + (k + 3) * 128 + tc * 4);
            const float* w0f = (const float*)&w0;
            const float* w1f = (const float*)&w1;
            const float* w2f = (const float*)&w2;
            const float* w3f = (const float*)&w3;
            #pragma unroll
            for (int i = 0; i < 4; ++i) {
                const float4 xv = *(const float4*)(xs + (tr * 4 + i) * 132 + kh * 64 + k);
                const float* xf = (const float*)&xv;
                #pragma unroll
                for (int j = 0; j < 4; ++j) {
                    acc[i][j] += xf[0] * w0f[j];
                    acc[i][j] += xf[1] * w1f[j];
                    acc[i][j] += xf[2] * w2f[j];
                    acc[i][j] += xf[3] * w3f[j];
                }
            }
        }
    }

    // ---- epilogue ----
    const int c0 = (tc & 15) * 4;
    if (tc < 16) {
        #pragma unroll
        for (int i = 0; i < 4; ++i) {
            const int n = n0 + tr * 4 + i;
            if (n < N)
                *(float4*)(y_rel + (size_t)n * HID + c0) =
                    make_float4(acc[i][0], acc[i][1], acc[i][2], acc[i][3]);
        }
    } else {
        const float4 br = *(const float4*)(b_rel + c0);
        #pragma unroll
        for (int i = 0; i < 4; ++i) {
            const int n = n0 + tr * 4 + i;
            if (n < N)
                *(float4*)(agg + (size_t)n * HID + c0) =
                    make_float4(acc[i][0] + br.x, acc[i][1] + br.y,
                                acc[i][2] + br.z, acc[i][3] + br.w);
        }
    }
}

// ---------------------------------------------------------------------------
// Kernel 2: edge scatter. 32 threads per edge, each adds a float2 of
// y_rel[src] into agg[dst] via HW f32 atomics (agg was pre-initialized with
// x@W_root + b_rel by the encoder).
// ---------------------------------------------------------------------------
__global__ __launch_bounds__(256) void graphmae_scatter(
    const int* __restrict__ ei, const float* __restrict__ y_rel,
    float* __restrict__ agg, int E)
{
    const int gid = blockIdx.x * 256 + threadIdx.x;
    const int e = gid >> 5;
    if (e >= E) return;
    const int j = (gid & 31) * 2;
    const int s = ei[e];         // src row
    const int d = ei[E + e];     // dst row
    const float2 v = *(const float2*)(y_rel + (size_t)s * HID + j);
    unsafeAtomicAdd(agg + (size_t)d * HID + j,     v.x);
    unsafeAtomicAdd(agg + (size_t)d * HID + j + 1, v.y);
}

// ---------------------------------------------------------------------------
// Kernel 3: decoder.  out[n][c] = sum_k relu(agg[n][k]) * W_dec[k][c] + b_dec[c]
// Same register-blocked structure; W_dec (32 KB) staged whole.
// ---------------------------------------------------------------------------
__global__ __launch_bounds__(256) void graphmae_decode(
    const float* __restrict__ agg, const float* __restrict__ W_dec,
    const float* __restrict__ b_dec, float* __restrict__ out, int N)
{
    __shared__ float wd[64 * 128];   // W_dec, row=k (0..63), col=c (0..127)
    __shared__ float hs[32 * 68];    // relu(agg) tile, padded 64->68

    const int t  = threadIdx.x;
    const int tc = t & 31;
    const int tr = t >> 5;
    const int n0 = blockIdx.x * 32;

    #pragma unroll
    for (int p = 0; p < 8; ++p) {
        const int idx = t + p * 256;   // float4 index 0..2047
        *(float4*)(wd + idx * 4) = *(const float4*)(W_dec + (size_t)idx * 4);
    }
    #pragma unroll
    for (int p = 0; p < 2; ++p) {
        const int idx = t + p * 256;      // float4 index 0..511
        const int row = idx >> 4;         // 0..31
        const int c4  = (idx & 15) * 4;   // 0..60
        const int n = n0 + row;
        float4 v = make_float4(0.f, 0.f, 0.f, 0.f);
        if (n < N) v = *(const float4*)(agg + (size_t)n * HID + c4);
        v.x = fmaxf(v.x, 0.f); v.y = fmaxf(v.y, 0.f);
        v.z = fmaxf(v.z, 0.f); v.w = fmaxf(v.w, 0.f);
        *(float4*)(hs + row * 68 + c4) = v;
    }
    __syncthreads();

    float acc[4][4];
    #pragma unroll
    for (int i = 0; i < 4; ++i)
        #pragma unroll
        for (int j = 0; j < 4; ++j) acc[i][j] = 0.f;

    const int c0 = tc * 4;
    #pragma unroll 2
    for (int k = 0; k < 64; k += 4) {
        float4 w0 = *(const float4*)(wd + (k + 0) * 128 + c0);
        float4 w1 = *(const float4*)(wd + (k + 1) * 128 + c0);
        float4 w2 = *(const float4*)(wd + (k + 2) * 128 + c0);
        float4 w3 = *(const float4*)(wd + (k + 3) * 128 + c0);
        const float* w0f = (const float*)&w0;
        const float* w1f = (const float*)&w1;
        const float* w2f = (const float*)&w2;
        const float* w3f = (const float*)&w3;
        #pragma unroll
        for (int i = 0; i < 4; ++i) {
            const float4 hv = *(const float4*)(hs + (tr * 4 + i) * 68 + k);
            const float* hf = (const float*)&hv;
            #pragma unroll
            for (int j = 0; j < 4; ++j) {
                acc[i][j] += hf[0] * w0f[j];
                acc[i][j] += hf[1] * w1f[j];
                acc[i][j] += hf[2] * w2f[j];
                acc[i][j] += hf[3] * w3f[j];
            }
        }
    }

    const float4 bd = *(const float4*)(b_dec + c0);
    #pragma unroll
    for (int i = 0; i < 4; ++i) {
        const int n = n0 + tr * 4 + i;
        if (n < N)
            *(float4*)(out + (size_t)n * IN_CH + c0) =
                make_float4(acc[i][0] + bd.x, acc[i][1] + bd.y,
                            acc[i][2] + bd.z, acc[i][3] + bd.w);
    }
}

// ---------------------------------------------------------------------------
extern "C" void kernel_launch(void* const* d_in, const int* in_sizes, int n_in,
                              void* d_out, int out_size, void* d_ws, size_t ws_size,
                              hipStream_t stream)
{
    const float* x      = (const float*)d_in[0];
    const int*   ei     = (const int*)  d_in[1];   // [2][E] int32
    const float* W_rel  = (const float*)d_in[2];
    const float* b_rel  = (const float*)d_in[3];
    const float* W_root = (const float*)d_in[4];
    const float* W_dec  = (const float*)d_in[5];
    const float* b_dec  = (const float*)d_in[6];
    float* out = (float*)d_out;

    const int N = in_sizes[0] / IN_CH;
    const int E = in_sizes[1] / 2;

    float* y_rel = (float*)d_ws;                     // [N][64]  12.8 MB
    float* agg   = y_rel + (size_t)N * HID;          // [N][64]  12.8 MB

    const int nblk = (N + 31) / 32;
    graphmae_encode<<<nblk, 256, 0, stream>>>(x, W_rel, b_rel, W_root, y_rel, agg, N);

    const long long sc_threads = (long long)E * 32;
    const int sc_blocks = (int)((sc_threads + 255) / 256);
    graphmae_scatter<<<sc_blocks, 256, 0, stream>>>(ei, y_rel, agg, E);

    graphmae_decode<<<nblk, 256, 0, stream>>>(agg, W_dec, b_dec, out, N);
}

// Round 2
// 151.759 us; speedup vs baseline: 1.9871x; 1.9871x over previous
//
#include <hip/hip_runtime.h>

#define IN_CH 128
#define HID 64
#define SCAN_CHUNK 1024   // elements scanned per block in scanA (256 thr x 4)

// ---------------------------------------------------------------------------
// Kernel 1: fused encoder GEMMs.
//   y_rel[n][c] = sum_k x[n][k] * W_rel[k][c]
//   agg[n][c]   = sum_k x[n][k] * W_root[k][c] + b_rel[c]   (gather target init)
// ---------------------------------------------------------------------------
__global__ __launch_bounds__(256) void graphmae_encode(
    const float* __restrict__ x, const float* __restrict__ W_rel,
    const float* __restrict__ b_rel, const float* __restrict__ W_root,
    float* __restrict__ y_rel, float* __restrict__ agg, int N)
{
    __shared__ float lw[64 * 128];   // k-half of [W_rel | W_root]
    __shared__ float xs[32 * 132];   // 32 x-rows, padded

    const int t  = threadIdx.x;
    const int tc = t & 31;
    const int tr = t >> 5;
    const int n0 = blockIdx.x * 32;

    #pragma unroll
    for (int p = 0; p < 4; ++p) {
        const int row = tr + p * 8;
        const int n   = n0 + row;
        float4 v = make_float4(0.f, 0.f, 0.f, 0.f);
        if (n < N) v = *(const float4*)(x + (size_t)n * IN_CH + tc * 4);
        *(float4*)(xs + row * 132 + tc * 4) = v;
    }

    float acc[4][4];
    #pragma unroll
    for (int i = 0; i < 4; ++i)
        #pragma unroll
        for (int j = 0; j < 4; ++j) acc[i][j] = 0.f;

    for (int kh = 0; kh < 2; ++kh) {
        __syncthreads();
        #pragma unroll
        for (int p = 0; p < 8; ++p) {
            const int idx  = t + p * 256;
            const int krow = idx >> 5;
            const int col4 = (idx & 31) * 4;
            float4 v;
            if (col4 < HID)
                v = *(const float4*)(W_rel  + (size_t)(kh * 64 + krow) * HID + col4);
            else
                v = *(const float4*)(W_root + (size_t)(kh * 64 + krow) * HID + (col4 - HID));
            *(float4*)(lw + idx * 4) = v;
        }
        __syncthreads();

        #pragma unroll 2
        for (int k = 0; k < 64; k += 4) {
            float4 w0 = *(const float4*)(lw + (k + 0) * 128 + tc * 4);
            float4 w1 = *(const float4*)(lw + (k + 1) * 128 + tc * 4);
            float4 w2 = *(const float4*)(lw + (k + 2) * 128 + tc * 4);
            float4 w3 = *(const float4*)(lw + (k + 3) * 128 + tc * 4);
            const float* w0f = (const float*)&w0;
            const float* w1f = (const float*)&w1;
            const float* w2f = (const float*)&w2;
            const float* w3f = (const float*)&w3;
            #pragma unroll
            for (int i = 0; i < 4; ++i) {
                const float4 xv = *(const float4*)(xs + (tr * 4 + i) * 132 + kh * 64 + k);
                const float* xf = (const float*)&xv;
                #pragma unroll
                for (int j = 0; j < 4; ++j) {
                    acc[i][j] += xf[0] * w0f[j];
                    acc[i][j] += xf[1] * w1f[j];
                    acc[i][j] += xf[2] * w2f[j];
                    acc[i][j] += xf[3] * w3f[j];
                }
            }
        }
    }

    const int c0 = (tc & 15) * 4;
    if (tc < 16) {
        #pragma unroll
        for (int i = 0; i < 4; ++i) {
            const int n = n0 + tr * 4 + i;
            if (n < N)
                *(float4*)(y_rel + (size_t)n * HID + c0) =
                    make_float4(acc[i][0], acc[i][1], acc[i][2], acc[i][3]);
        }
    } else {
        const float4 br = *(const float4*)(b_rel + c0);
        #pragma unroll
        for (int i = 0; i < 4; ++i) {
            const int n = n0 + tr * 4 + i;
            if (n < N)
                *(float4*)(agg + (size_t)n * HID + c0) =
                    make_float4(acc[i][0] + br.x, acc[i][1] + br.y,
                                acc[i][2] + br.z, acc[i][3] + br.w);
        }
    }
}

// ---------------------------------------------------------------------------
// CSR build: zero -> count -> scan(A,B,C) -> fill
// ---------------------------------------------------------------------------
__global__ __launch_bounds__(256) void csr_zero(int* __restrict__ deg, int N)
{
    const int i = blockIdx.x * 256 + threadIdx.x;
    if (i < N) deg[i] = 0;
}

__global__ __launch_bounds__(256) void csr_count(
    const int* __restrict__ ei, int* __restrict__ deg, int E)
{
    const int e = blockIdx.x * 256 + threadIdx.x;
    if (e < E) atomicAdd(&deg[ei[E + e]], 1);
}

// per-block exclusive scan of 1024-element chunks; block totals to bsum
__global__ __launch_bounds__(256) void csr_scanA(
    const int* __restrict__ deg, int* __restrict__ row_start,
    int* __restrict__ bsum, int N)
{
    __shared__ int sd[256];
    const int t    = threadIdx.x;
    const int base = blockIdx.x * SCAN_CHUNK + t * 4;

    int d[4];
    #pragma unroll
    for (int j = 0; j < 4; ++j) d[j] = (base + j < N) ? deg[base + j] : 0;
    const int tsum = d[0] + d[1] + d[2] + d[3];

    sd[t] = tsum;
    __syncthreads();
    for (int off = 1; off < 256; off <<= 1) {
        const int v = (t >= off) ? sd[t - off] : 0;
        __syncthreads();
        sd[t] += v;
        __syncthreads();
    }
    int run = sd[t] - tsum;   // exclusive prefix of this thread within block
    #pragma unroll
    for (int j = 0; j < 4; ++j) {
        if (base + j < N) row_start[base + j] = run;
        run += d[j];
    }
    if (t == 255) bsum[blockIdx.x] = sd[255];
}

// serial exclusive scan of block sums (NB ~ 49) + write row_start[N]
__global__ void csr_scanB(int* __restrict__ bsum, int* __restrict__ row_start,
                          int NB, int N, int E)
{
    if (threadIdx.x == 0 && blockIdx.x == 0) {
        int acc = 0;
        for (int i = 0; i < NB; ++i) { const int v = bsum[i]; bsum[i] = acc; acc += v; }
        row_start[N] = E;
    }
}

__global__ __launch_bounds__(256) void csr_scanC(
    int* __restrict__ row_start, int* __restrict__ cursor,
    const int* __restrict__ bsum, int N)
{
    const int i = blockIdx.x * 256 + threadIdx.x;
    if (i < N) {
        const int v = row_start[i] + bsum[i / SCAN_CHUNK];
        row_start[i] = v;
        cursor[i] = v;
    }
}

__global__ __launch_bounds__(256) void csr_fill(
    const int* __restrict__ ei, int* __restrict__ cursor,
    int* __restrict__ col, int E)
{
    const int e = blockIdx.x * 256 + threadIdx.x;
    if (e < E) {
        const int s = ei[e];
        const int d = ei[E + e];
        const int p = atomicAdd(&cursor[d], 1);
        col[p] = s;
    }
}

// ---------------------------------------------------------------------------
// Kernel 2: gather-sum. One wave64 per node: 4 edge-slots x 16 col-lanes.
// agg[n] += sum over incoming edges of y_rel[src]. No float atomics.
// ---------------------------------------------------------------------------
__global__ __launch_bounds__(256) void graphmae_gather(
    const int* __restrict__ row_start, const int* __restrict__ col,
    const float* __restrict__ y_rel, float* __restrict__ agg, int N)
{
    const int wave = (blockIdx.x * 256 + threadIdx.x) >> 6;
    const int lane = threadIdx.x & 63;
    if (wave >= N) return;
    const int n  = wave;
    const int es = lane >> 4;     // edge slot 0..3
    const int cl = lane & 15;     // column lane: floats cl*4 .. cl*4+3

    const int beg = row_start[n];
    const int end = row_start[n + 1];

    float4 acc = make_float4(0.f, 0.f, 0.f, 0.f);
    for (int e = beg + es; e < end; e += 4) {
        const int s = col[e];
        const float4 v = *(const float4*)(y_rel + (size_t)s * HID + cl * 4);
        acc.x += v.x; acc.y += v.y; acc.z += v.z; acc.w += v.w;
    }
    // reduce across the 4 edge slots (lane bits 4,5)
    acc.x += __shfl_xor(acc.x, 16); acc.y += __shfl_xor(acc.y, 16);
    acc.z += __shfl_xor(acc.z, 16); acc.w += __shfl_xor(acc.w, 16);
    acc.x += __shfl_xor(acc.x, 32); acc.y += __shfl_xor(acc.y, 32);
    acc.z += __shfl_xor(acc.z, 32); acc.w += __shfl_xor(acc.w, 32);

    if (es == 0) {
        float4 o = *(const float4*)(agg + (size_t)n * HID + cl * 4);
        o.x += acc.x; o.y += acc.y; o.z += acc.z; o.w += acc.w;
        *(float4*)(agg + (size_t)n * HID + cl * 4) = o;
    }
}

// ---------------------------------------------------------------------------
// Kernel 3: decoder.  out[n][c] = sum_k relu(agg[n][k]) * W_dec[k][c] + b_dec[c]
// ---------------------------------------------------------------------------
__global__ __launch_bounds__(256) void graphmae_decode(
    const float* __restrict__ agg, const float* __restrict__ W_dec,
    const float* __restrict__ b_dec, float* __restrict__ out, int N)
{
    __shared__ float wd[64 * 128];
    __shared__ float hs[32 * 68];

    const int t  = threadIdx.x;
    const int tc = t & 31;
    const int tr = t >> 5;
    const int n0 = blockIdx.x * 32;

    #pragma unroll
    for (int p = 0; p < 8; ++p) {
        const int idx = t + p * 256;
        *(float4*)(wd + idx * 4) = *(const float4*)(W_dec + (size_t)idx * 4);
    }
    #pragma unroll
    for (int p = 0; p < 2; ++p) {
        const int idx = t + p * 256;
        const int row = idx >> 4;
        const int c4  = (idx & 15) * 4;
        const int n = n0 + row;
        float4 v = make_float4(0.f, 0.f, 0.f, 0.f);
        if (n < N) v = *(const float4*)(agg + (size_t)n * HID + c4);
        v.x = fmaxf(v.x, 0.f); v.y = fmaxf(v.y, 0.f);
        v.z = fmaxf(v.z, 0.f); v.w = fmaxf(v.w, 0.f);
        *(float4*)(hs + row * 68 + c4) = v;
    }
    __syncthreads();

    float acc[4][4];
    #pragma unroll
    for (int i = 0; i < 4; ++i)
        #pragma unroll
        for (int j = 0; j < 4; ++j) acc[i][j] = 0.f;

    const int c0 = tc * 4;
    #pragma unroll 2
    for (int k = 0; k < 64; k += 4) {
        float4 w0 = *(const float4*)(wd + (k + 0) * 128 + c0);
        float4 w1 = *(const float4*)(wd + (k + 1) * 128 + c0);
        float4 w2 = *(const float4*)(wd + (k + 2) * 128 + c0);
        float4 w3 = *(const float4*)(wd + (k + 3) * 128 + c0);
        const float* w0f = (const float*)&w0;
        const float* w1f = (const float*)&w1;
        const float* w2f = (const float*)&w2;
        const float* w3f = (const float*)&w3;
        #pragma unroll
        for (int i = 0; i < 4; ++i) {
            const float4 hv = *(const float4*)(hs + (tr * 4 + i) * 68 + k);
            const float* hf = (const float*)&hv;
            #pragma unroll
            for (int j = 0; j < 4; ++j) {
                acc[i][j] += hf[0] * w0f[j];
                acc[i][j] += hf[1] * w1f[j];
                acc[i][j] += hf[2] * w2f[j];
                acc[i][j] += hf[3] * w3f[j];
            }
        }
    }

    const float4 bd = *(const float4*)(b_dec + c0);
    #pragma unroll
    for (int i = 0; i < 4; ++i) {
        const int n = n0 + tr * 4 + i;
        if (n < N)
            *(float4*)(out + (size_t)n * IN_CH + c0) =
                make_float4(acc[i][0] + bd.x, acc[i][1] + bd.y,
                            acc[i][2] + bd.z, acc[i][3] + bd.w);
    }
}

// ---------------------------------------------------------------------------
extern "C" void kernel_launch(void* const* d_in, const int* in_sizes, int n_in,
                              void* d_out, int out_size, void* d_ws, size_t ws_size,
                              hipStream_t stream)
{
    const float* x      = (const float*)d_in[0];
    const int*   ei     = (const int*)  d_in[1];   // [2][E] int32
    const float* W_rel  = (const float*)d_in[2];
    const float* b_rel  = (const float*)d_in[3];
    const float* W_root = (const float*)d_in[4];
    const float* W_dec  = (const float*)d_in[5];
    const float* b_dec  = (const float*)d_in[6];
    float* out = (float*)d_out;

    const int N = in_sizes[0] / IN_CH;
    const int E = in_sizes[1] / 2;

    float* y_rel     = (float*)d_ws;                    // [N][64]
    float* agg       = y_rel + (size_t)N * HID;         // [N][64]
    int*   row_start = (int*)(agg + (size_t)N * HID);   // [N+1]
    int*   cursor    = row_start + (N + 1);             // [N]
    int*   deg       = cursor + N;                      // [N]
    int*   col       = deg + N;                         // [E]
    int*   bsum      = col + E;                         // [NB]

    const int nblk  = (N + 31) / 32;
    const int nthr  = (N + 255) / 256;
    const int ethr  = (E + 255) / 256;
    const int NB    = (N + SCAN_CHUNK - 1) / SCAN_CHUNK;

    graphmae_encode<<<nblk, 256, 0, stream>>>(x, W_rel, b_rel, W_root, y_rel, agg, N);

    csr_zero <<<nthr, 256, 0, stream>>>(deg, N);
    csr_count<<<ethr, 256, 0, stream>>>(ei, deg, E);
    csr_scanA<<<NB,   256, 0, stream>>>(deg, row_start, bsum, N);
    csr_scanB<<<1,     64, 0, stream>>>(bsum, row_start, NB, N, E);
    csr_scanC<<<nthr, 256, 0, stream>>>(row_start, cursor, bsum, N);
    csr_fill <<<ethr, 256, 0, stream>>>(ei, cursor, col, E);

    const int gblk = (N * 64 + 255) / 256;   // one wave64 per node
    graphmae_gather<<<gblk, 256, 0, stream>>>(row_start, col, y_rel, agg, N);

    graphmae_decode<<<nblk, 256, 0, stream>>>(agg, W_dec, b_dec, out, N);
}